// Round 4
// baseline (158.423 us; speedup 1.0000x reference)
//
#include <hip/hip_runtime.h>
#include <cstdint>

// Lukasiewicz max-plus matmul: y[n,o] = max(b[o], max(0, max_i(x[n,i]+a[o,i]-1)))
// N=2048, K=512, OUT=512, fp32.
//
// R4: register-only dataflow. R3 proved scalar-path X is a trap (SMEM returns
// OOO -> lgkmcnt(0) full-drain kills pipelining). Now: block = 32 rows x 64
// cols x full K; col = tid&63 (a-loads coalesced from transposed Ap4); each
// wave owns 8 rows (x loads wave-uniform VECTOR loads -> 1 L2 line, in-order
// vmcnt, deeply pipelinable). No LDS, no barriers, no K-split, no atomics.
// Traffic: A 64MB + X 32MB from L2 (~10 TB/s at 10us << 34.5 ceiling).

#define NROW 2048
#define NK   512
#define NCOL 512
#define RP   32                   // rows per block (8 per wave)
#define CB   64                   // cols per block
typedef float f32x4 __attribute__((ext_vector_type(4)));

// ---- prep: Ap4[k4*512 + col] = {A[col][4k4+0..3]} -------------------------
__global__ __launch_bounds__(256) void luka_prep(const float* __restrict__ A,
                                                 f32x4* __restrict__ Ap4) {
  int idx = blockIdx.x * 256 + threadIdx.x;  // 512 cols * 128 k4
  int o  = idx >> 7;
  int k4 = idx & 127;
  f32x4 v = *(const f32x4*)(A + o * NK + k4 * 4);  // coalesced along k
  Ap4[k4 * NCOL + o] = v;                          // 1MB one-shot
}

// ---- main -----------------------------------------------------------------
__global__ __launch_bounds__(256) void luka_main(
    const f32x4* __restrict__ Ap4, const float* __restrict__ X,
    const float* __restrict__ Bv, float* __restrict__ Y) {
  const int tid  = threadIdx.x;
  const int lane = tid & 63;
  const int col  = blockIdx.x * CB + lane;          // per-lane distinct
  const int row0 = blockIdx.y * RP + (tid >> 6) * 8; // wave-uniform 8-row slab

  const f32x4* __restrict__ Ap = Ap4 + col;                  // stride 512/k4
  const f32x4* __restrict__ Xp = (const f32x4*)X + (size_t)row0 * (NK / 4);

  float acc[8];
#pragma unroll
  for (int r = 0; r < 8; ++r) acc[r] = 0.0f;  // exact: ref clamps at 0 anyway

#pragma unroll 4
  for (int k4 = 0; k4 < NK / 4; ++k4) {
    const f32x4 av = Ap[(size_t)k4 * NCOL];   // 1KB coalesced wave txn
#pragma unroll
    for (int r = 0; r < 8; ++r) {
      const f32x4 xv = Xp[r * (NK / 4) + k4]; // wave-uniform -> 1 L2 line
      f32x4 s = av + xv;                      // 2x v_pk_add_f32
      acc[r] = fmaxf(fmaxf(s.x, s.y), acc[r]);  // v_max3_f32
      acc[r] = fmaxf(fmaxf(s.z, s.w), acc[r]);  // v_max3_f32
    }
  }

  // y = max3(acc-1, b, 0); exact: rounding monotone, same argmax; b,0 >= 0.
  const float bv = Bv[col];
#pragma unroll
  for (int r = 0; r < 8; ++r) {
    float t = acc[r] - 1.0f;
    Y[(size_t)(row0 + r) * NCOL + col] = fmaxf(fmaxf(t, bv), 0.0f);
  }
}

// ---- fallback (R1 kernel, used only if d_ws < 1MB) ------------------------
#define TILE 64
#define BK   64
__device__ __forceinline__ void async_load16(const float* g, float* l) {
  __builtin_amdgcn_global_load_lds(
      (const __attribute__((address_space(1))) void*)g,
      (__attribute__((address_space(3))) void*)l, 16, 0, 0);
}
__global__ __launch_bounds__(256) void luka_fb(
    const float* __restrict__ X, const float* __restrict__ A,
    const float* __restrict__ Bv, float* __restrict__ Y) {
  __shared__ float xs[2][TILE * BK];
  __shared__ float as[2][TILE * BK];
  const int tid = threadIdx.x, wave = tid >> 6, tx = tid & 15, ty = tid >> 4;
  const int rowBase = blockIdx.y * TILE, colBase = blockIdx.x * TILE;
  uint32_t xoff[4], aoff[4];
#pragma unroll
  for (int r = 0; r < 4; ++r) {
    int row = ty * 4 + r;
    xoff[r] = (uint32_t)row * 256u + ((uint32_t)((row & 15) ^ (row >> 2)) << 4);
  }
#pragma unroll
  for (int c = 0; c < 4; ++c) {
    int row = tx * 4 + c;
    aoff[c] = (uint32_t)row * 256u + ((uint32_t)((row & 15) ^ (row >> 2)) << 4);
  }
  float acc[4][4];
#pragma unroll
  for (int r = 0; r < 4; ++r)
#pragma unroll
    for (int c = 0; c < 4; ++c) acc[r][c] = 0.0f;
  const int row0 = tid >> 4, sl = tid & 15;
  auto stage = [&](int buf, int kt) {
#pragma unroll
    for (int j = 0; j < 4; ++j) {
      int row = row0 + j * 16;
      int m = (row & 15) ^ (row >> 2);
      int kk = ((sl ^ m) << 2);
      async_load16(X + (size_t)(rowBase + row) * NK + kt * BK + kk,
                   &xs[buf][j * 1024 + wave * 256]);
      async_load16(A + (size_t)(colBase + row) * NK + kt * BK + kk,
                   &as[buf][j * 1024 + wave * 256]);
    }
  };
  stage(0, 0);
  __syncthreads();
  int buf = 0;
#pragma unroll 1
  for (int kt = 0; kt < NK / BK; ++kt) {
    if (kt < NK / BK - 1) stage(buf ^ 1, kt + 1);
    const char* xb = (const char*)&xs[buf][0];
    const char* ab = (const char*)&as[buf][0];
#pragma unroll
    for (int s4 = 0; s4 < BK / 4; ++s4) {
      f32x4 xf[4], af[4];
#pragma unroll
      for (int r = 0; r < 4; ++r)
        xf[r] = *(const f32x4*)(xb + (xoff[r] ^ (uint32_t)(s4 << 4)));
#pragma unroll
      for (int c = 0; c < 4; ++c)
        af[c] = *(const f32x4*)(ab + (aoff[c] ^ (uint32_t)(s4 << 4)));
#pragma unroll
      for (int r = 0; r < 4; ++r)
#pragma unroll
        for (int c = 0; c < 4; ++c) {
          f32x4 s = xf[r] + af[c];
          float t0 = fmaxf(fmaxf(s.x, s.y), acc[r][c]);
          acc[r][c] = fmaxf(fmaxf(s.z, s.w), t0);
        }
    }
    __syncthreads();
    buf ^= 1;
  }
  const f32x4 bv = *(const f32x4*)&Bv[colBase + tx * 4];
  float bvv[4] = {bv.x, bv.y, bv.z, bv.w};
#pragma unroll
  for (int r = 0; r < 4; ++r) {
    f32x4 o;
    o.x = fmaxf(fmaxf(acc[r][0] - 1.0f, bvv[0]), 0.0f);
    o.y = fmaxf(fmaxf(acc[r][1] - 1.0f, bvv[1]), 0.0f);
    o.z = fmaxf(fmaxf(acc[r][2] - 1.0f, bvv[2]), 0.0f);
    o.w = fmaxf(fmaxf(acc[r][3] - 1.0f, bvv[3]), 0.0f);
    *(f32x4*)&Y[(size_t)(rowBase + ty * 4 + r) * NCOL + colBase + tx * 4] = o;
  }
}

extern "C" void kernel_launch(void* const* d_in, const int* in_sizes, int n_in,
                              void* d_out, int out_size, void* d_ws, size_t ws_size,
                              hipStream_t stream) {
  const float* X = (const float*)d_in[0];   // [2048][512]
  const float* A = (const float*)d_in[1];   // [512][512]
  const float* B = (const float*)d_in[2];   // [512]
  float* Y = (float*)d_out;                 // [2048][512]

  if (ws_size >= (size_t)NCOL * NK * sizeof(float)) {
    f32x4* Ap4 = (f32x4*)d_ws;
    luka_prep<<<dim3(NCOL * NK / 4 / 256), dim3(256), 0, stream>>>(A, Ap4);
    dim3 grid(NCOL / CB, NROW / RP);        // (8, 64) = 512 blocks
    luka_main<<<grid, dim3(256), 0, stream>>>(Ap4, X, B, Y);
  } else {
    dim3 grid(NCOL / TILE, NROW / TILE);    // fallback: R1 kernel
    luka_fb<<<grid, dim3(256), 0, stream>>>(X, A, B, Y);
  }
}

// Round 5
// 132.881 us; speedup vs baseline: 1.1922x; 1.1922x over previous
//
#include <hip/hip_runtime.h>
#include <cstdint>

// Lukasiewicz max-plus matmul: y[n,o] = max(b[o], max(0, max_i(x[n,i]+a[o,i]-1)))
// N=2048, K=512, OUT=512, fp32.
//
// R5: duplicate-free k-split. Block = 16 rows x 64 cols (lane=col); each of
// the 4 waves owns a K-quarter -> every global load in the block is unique
// (no LDS operand streaming [R2: LDS-BW-bound], no s_load [R3: OOO drain],
// no wave-duplicate loads). Partial maxes merged via one 16KB LDS pass.
// Grid = 1024 blocks = 4/CU = 4 waves/SIMD (R1/R4 died at 2/SIMD).
// A pre-transposed to Apb[colblk][k4][col] so a-loads are coalesced with
// +1KB stride; x-loads wave-uniform with all-immediate offsets (j*16 < 4KB).

#define NROW 2048
#define NK   512
#define NCOL 512
#define RPB  16                   // rows per block (shared by all waves)
#define CB   64                   // cols per block (lane = col)
#define KQ   32                   // k4-steps per wave (128 total / 4 waves)
typedef float f32x4 __attribute__((ext_vector_type(4)));

// ---- prep: Apb[((col>>6)*128 + k4)*64 + (col&63)] = A[col][4k4..4k4+3] ----
__global__ __launch_bounds__(256) void luka_prep(const float* __restrict__ A,
                                                 f32x4* __restrict__ Apb) {
  int idx = blockIdx.x * 256 + threadIdx.x;   // 512 cols * 128 k4
  int o  = idx >> 7;
  int k4 = idx & 127;
  f32x4 v = *(const f32x4*)(A + o * NK + k4 * 4);     // coalesced read
  Apb[(((o >> 6) * 128) + k4) * 64 + (o & 63)] = v;   // 1MB one-shot
}

// ---- main -----------------------------------------------------------------
__global__ __launch_bounds__(256, 4) void luka_main(
    const f32x4* __restrict__ Apb, const float* __restrict__ X,
    const float* __restrict__ Bv, float* __restrict__ Y) {
  const int tid  = threadIdx.x;
  const int lane = tid & 63;
  const int w    = tid >> 6;                  // wave id = K-quarter
  const int colblk  = blockIdx.x;             // 0..7  (== XCD under RR dispatch)
  const int rowBase = blockIdx.y * RPB;

  // wave's a-stream: Apb slice for (colblk, k-quarter w), advancing 64 f32x4/step
  const f32x4* __restrict__ Aw = Apb + ((size_t)(colblk * 128 + w * KQ) * 64 + lane);
  // wave's x-stream: rows rowBase..rowBase+15, k-quarter w (wave-uniform addrs)
  const f32x4* __restrict__ Xq = (const f32x4*)X + (size_t)rowBase * (NK / 4) + w * KQ;

  float acc[RPB];
#pragma unroll
  for (int r = 0; r < RPB; ++r) acc[r] = 0.0f;   // exact: ref clamps at 0

#pragma unroll 2
  for (int j = 0; j < KQ; ++j) {
    const f32x4 av = Aw[j * 64];                 // 1KB coalesced wave txn
#pragma unroll
    for (int r = 0; r < RPB; ++r) {
      const f32x4 xv = Xq[r * (NK / 4) + j];     // wave-uniform, imm offset
      f32x4 s = av + xv;                         // 2x v_pk_add_f32
      acc[r] = fmaxf(fmaxf(s.x, s.y), acc[r]);   // v_max3_f32
      acc[r] = fmaxf(fmaxf(s.z, s.w), acc[r]);   // v_max3_f32
    }
  }

  // merge K-quarters: max across the 4 waves (assoc -> exact)
  __shared__ float red[4][RPB][CB];              // 16KB
#pragma unroll
  for (int r = 0; r < RPB; ++r) red[w][r][lane] = acc[r];
  __syncthreads();

  const float bv = Bv[colblk * CB + lane];
#pragma unroll
  for (int i = 0; i < 4; ++i) {
    int r = w * 4 + i;                           // wave w finalizes rows 4w..4w+3
    float m = fmaxf(fmaxf(red[0][r][lane], red[1][r][lane]),
                    fmaxf(red[2][r][lane], red[3][r][lane]));
    float t = m - 1.0f;                          // defer of -1 is exact
    Y[(size_t)(rowBase + r) * NCOL + colblk * CB + lane] =
        fmaxf(fmaxf(t, bv), 0.0f);               // v_max3_f32
  }
}

// ---- fallback (R1 kernel, used only if d_ws < 1MB) ------------------------
#define TILE 64
#define BK   64
__device__ __forceinline__ void async_load16(const float* g, float* l) {
  __builtin_amdgcn_global_load_lds(
      (const __attribute__((address_space(1))) void*)g,
      (__attribute__((address_space(3))) void*)l, 16, 0, 0);
}
__global__ __launch_bounds__(256) void luka_fb(
    const float* __restrict__ X, const float* __restrict__ A,
    const float* __restrict__ Bv, float* __restrict__ Y) {
  __shared__ float xs[2][TILE * BK];
  __shared__ float as[2][TILE * BK];
  const int tid = threadIdx.x, wave = tid >> 6, tx = tid & 15, ty = tid >> 4;
  const int rowBase = blockIdx.y * TILE, colBase = blockIdx.x * TILE;
  uint32_t xoff[4], aoff[4];
#pragma unroll
  for (int r = 0; r < 4; ++r) {
    int row = ty * 4 + r;
    xoff[r] = (uint32_t)row * 256u + ((uint32_t)((row & 15) ^ (row >> 2)) << 4);
  }
#pragma unroll
  for (int c = 0; c < 4; ++c) {
    int row = tx * 4 + c;
    aoff[c] = (uint32_t)row * 256u + ((uint32_t)((row & 15) ^ (row >> 2)) << 4);
  }
  float acc[4][4];
#pragma unroll
  for (int r = 0; r < 4; ++r)
#pragma unroll
    for (int c = 0; c < 4; ++c) acc[r][c] = 0.0f;
  const int row0 = tid >> 4, sl = tid & 15;
  auto stage = [&](int buf, int kt) {
#pragma unroll
    for (int j = 0; j < 4; ++j) {
      int row = row0 + j * 16;
      int m = (row & 15) ^ (row >> 2);
      int kk = ((sl ^ m) << 2);
      async_load16(X + (size_t)(rowBase + row) * NK + kt * BK + kk,
                   &xs[buf][j * 1024 + wave * 256]);
      async_load16(A + (size_t)(colBase + row) * NK + kt * BK + kk,
                   &as[buf][j * 1024 + wave * 256]);
    }
  };
  stage(0, 0);
  __syncthreads();
  int buf = 0;
#pragma unroll 1
  for (int kt = 0; kt < NK / BK; ++kt) {
    if (kt < NK / BK - 1) stage(buf ^ 1, kt + 1);
    const char* xb = (const char*)&xs[buf][0];
    const char* ab = (const char*)&as[buf][0];
#pragma unroll
    for (int s4 = 0; s4 < BK / 4; ++s4) {
      f32x4 xf[4], af[4];
#pragma unroll
      for (int r = 0; r < 4; ++r)
        xf[r] = *(const f32x4*)(xb + (xoff[r] ^ (uint32_t)(s4 << 4)));
#pragma unroll
      for (int c = 0; c < 4; ++c)
        af[c] = *(const f32x4*)(ab + (aoff[c] ^ (uint32_t)(s4 << 4)));
#pragma unroll
      for (int r = 0; r < 4; ++r)
#pragma unroll
        for (int c = 0; c < 4; ++c) {
          f32x4 s = xf[r] + af[c];
          float t0 = fmaxf(fmaxf(s.x, s.y), acc[r][c]);
          acc[r][c] = fmaxf(fmaxf(s.z, s.w), t0);
        }
    }
    __syncthreads();
    buf ^= 1;
  }
  const f32x4 bv = *(const f32x4*)&Bv[colBase + tx * 4];
  float bvv[4] = {bv.x, bv.y, bv.z, bv.w};
#pragma unroll
  for (int r = 0; r < 4; ++r) {
    f32x4 o;
    o.x = fmaxf(fmaxf(acc[r][0] - 1.0f, bvv[0]), 0.0f);
    o.y = fmaxf(fmaxf(acc[r][1] - 1.0f, bvv[1]), 0.0f);
    o.z = fmaxf(fmaxf(acc[r][2] - 1.0f, bvv[2]), 0.0f);
    o.w = fmaxf(fmaxf(acc[r][3] - 1.0f, bvv[3]), 0.0f);
    *(f32x4*)&Y[(size_t)(rowBase + ty * 4 + r) * NCOL + colBase + tx * 4] = o;
  }
}

extern "C" void kernel_launch(void* const* d_in, const int* in_sizes, int n_in,
                              void* d_out, int out_size, void* d_ws, size_t ws_size,
                              hipStream_t stream) {
  const float* X = (const float*)d_in[0];   // [2048][512]
  const float* A = (const float*)d_in[1];   // [512][512]
  const float* B = (const float*)d_in[2];   // [512]
  float* Y = (float*)d_out;                 // [2048][512]

  if (ws_size >= (size_t)NCOL * NK * sizeof(float)) {
    f32x4* Apb = (f32x4*)d_ws;
    luka_prep<<<dim3(NCOL * NK / 4 / 256), dim3(256), 0, stream>>>(A, Apb);
    dim3 grid(NCOL / CB, NROW / RPB);       // (8, 128) = 1024 blocks, 4/CU
    luka_main<<<grid, dim3(256), 0, stream>>>(Apb, X, B, Y);
  } else {
    dim3 grid(NCOL / TILE, NROW / TILE);    // fallback: R1 kernel
    luka_fb<<<grid, dim3(256), 0, stream>>>(X, A, B, Y);
  }
}

// Round 6
// 87.958 us; speedup vs baseline: 1.8011x; 1.5107x over previous
//
#include <hip/hip_runtime.h>
#include <cstdint>

// Lukasiewicz max-plus matmul: y[n,o] = max(b[o], max(0, max_i(x[n,i]+a[o,i]-1)))
// N=2048, K=512, OUT=512, fp32.
//
// R6: full occupancy + split-pipe operands. 512-thr block (8 waves), 16 rows
// x 64 cols, 8-way K-split. X staged once to LDS (32KB) and consumed as
// wave-uniform broadcast ds_read_b128 (LDS pipe, conflict-free); A streamed
// per-lane from transposed Apb (L1 pipe, 1 VMEM/j-step). 1024 blocks = 4/CU
// = 8 waves/SIMD -> TLP alone hides L2 latency (R4/R5 died at low ILP + low
// TLP). Partial-max merge reuses the X LDS buffer (32KB total -> 4 blk/CU).

#define NROW 2048
#define NK   512
#define NCOL 512
#define RPB  16                   // rows per block
#define CB   64                   // cols per block (lane = col)
#define NW   8                    // waves per block
#define KQ   16                   // k4-steps per wave (128 / 8)
typedef float f32x4 __attribute__((ext_vector_type(4)));

__device__ __forceinline__ void async_load16(const float* g, float* l) {
  __builtin_amdgcn_global_load_lds(
      (const __attribute__((address_space(1))) void*)g,
      (__attribute__((address_space(3))) void*)l, 16, 0, 0);
}

// ---- prep: Apb[((col>>6)*128 + k4)*64 + (col&63)] = A[col][4k4..4k4+3] ----
__global__ __launch_bounds__(256) void luka_prep(const float* __restrict__ A,
                                                 f32x4* __restrict__ Apb) {
  int idx = blockIdx.x * 256 + threadIdx.x;   // 512 cols * 128 k4
  int o  = idx >> 7;
  int k4 = idx & 127;
  f32x4 v = *(const f32x4*)(A + o * NK + k4 * 4);     // coalesced read
  Apb[(((o >> 6) * 128) + k4) * 64 + (o & 63)] = v;   // 1MB one-shot
}

// ---- main -----------------------------------------------------------------
__global__ __launch_bounds__(512, 8) void luka_main(
    const f32x4* __restrict__ Apb, const float* __restrict__ X,
    const float* __restrict__ Bv, float* __restrict__ Y) {
  __shared__ float lds[RPB * NK];             // 32KB: X slab, then reduction
  const int tid  = threadIdx.x;
  const int lane = tid & 63;
  const int w    = tid >> 6;                  // wave id = K-eighth
  const int colblk  = blockIdx.x;             // 0..7
  const int rowBase = blockIdx.y * RPB;

  // Stage X[rowBase..+16)[0..512) -> lds, row-major [16][512]. 2048 f32x4 by
  // 512 threads = 4 rounds; per-wave dest is linear (base + lane*16) ✓.
  {
    const float* Xg = X + (size_t)rowBase * NK;
#pragma unroll
    for (int rnd = 0; rnd < 4; ++rnd) {
      int base = rnd * 512 + w * 64;          // f32x4 index, wave-uniform
      async_load16(Xg + (size_t)(base + lane) * 4, &lds[base * 4]);
    }
  }

  // Wave's A stream: colblk panel, k-quarter w (per-lane, coalesced 1KB txns)
  const f32x4* __restrict__ Aw =
      Apb + ((size_t)(colblk * 128 + w * KQ) * 64 + lane);

  float acc[RPB];
#pragma unroll
  for (int r = 0; r < RPB; ++r) acc[r] = 0.0f;   // exact: ref clamps at 0

  __syncthreads();                               // staged X visible (vm drain)

#pragma unroll 2
  for (int j = 0; j < KQ; ++j) {
    const f32x4 av = Aw[j * 64];                 // L1 pipe: 1KB coalesced
    const int kb = (w * KQ + j) * 4;             // float col within x row
#pragma unroll
    for (int r = 0; r < RPB; ++r) {
      // LDS pipe: wave-uniform broadcast ds_read_b128, conflict-free
      const f32x4 xv = *(const f32x4*)&lds[r * NK + kb];
      f32x4 s = av + xv;                         // 2x v_pk_add_f32
      acc[r] = fmaxf(fmaxf(s.x, s.y), acc[r]);   // v_max3_f32
      acc[r] = fmaxf(fmaxf(s.z, s.w), acc[r]);   // v_max3_f32
    }
  }

  // 8-way K-merge: reuse lds as red[8][16][64] (32KB). Barrier first: other
  // waves may still be reading the X slab.
  __syncthreads();
#pragma unroll
  for (int r = 0; r < RPB; ++r) lds[(w * RPB + r) * CB + lane] = acc[r];
  __syncthreads();

  const float bv = Bv[colblk * CB + lane];
#pragma unroll
  for (int i = 0; i < 2; ++i) {                  // wave w finalizes rows 2w,2w+1
    const int r = w * 2 + i;
    float m0 = fmaxf(fmaxf(lds[(0 * RPB + r) * CB + lane],
                           lds[(1 * RPB + r) * CB + lane]),
                     fmaxf(lds[(2 * RPB + r) * CB + lane],
                           lds[(3 * RPB + r) * CB + lane]));
    float m1 = fmaxf(fmaxf(lds[(4 * RPB + r) * CB + lane],
                           lds[(5 * RPB + r) * CB + lane]),
                     fmaxf(lds[(6 * RPB + r) * CB + lane],
                           lds[(7 * RPB + r) * CB + lane]));
    float t = fmaxf(m0, m1) - 1.0f;              // defer of -1 is exact
    Y[(size_t)(rowBase + r) * NCOL + colblk * CB + lane] =
        fmaxf(fmaxf(t, bv), 0.0f);               // v_max3_f32
  }
}

// ---- fallback (R1 kernel, used only if d_ws < 1MB) ------------------------
#define TILE 64
#define BK   64
__global__ __launch_bounds__(256) void luka_fb(
    const float* __restrict__ X, const float* __restrict__ A,
    const float* __restrict__ Bv, float* __restrict__ Y) {
  __shared__ float xs[2][TILE * BK];
  __shared__ float as[2][TILE * BK];
  const int tid = threadIdx.x, wave = tid >> 6, tx = tid & 15, ty = tid >> 4;
  const int rowBase = blockIdx.y * TILE, colBase = blockIdx.x * TILE;
  uint32_t xoff[4], aoff[4];
#pragma unroll
  for (int r = 0; r < 4; ++r) {
    int row = ty * 4 + r;
    xoff[r] = (uint32_t)row * 256u + ((uint32_t)((row & 15) ^ (row >> 2)) << 4);
  }
#pragma unroll
  for (int c = 0; c < 4; ++c) {
    int row = tx * 4 + c;
    aoff[c] = (uint32_t)row * 256u + ((uint32_t)((row & 15) ^ (row >> 2)) << 4);
  }
  float acc[4][4];
#pragma unroll
  for (int r = 0; r < 4; ++r)
#pragma unroll
    for (int c = 0; c < 4; ++c) acc[r][c] = 0.0f;
  const int row0 = tid >> 4, sl = tid & 15;
  auto stage = [&](int buf, int kt) {
#pragma unroll
    for (int j = 0; j < 4; ++j) {
      int row = row0 + j * 16;
      int m = (row & 15) ^ (row >> 2);
      int kk = ((sl ^ m) << 2);
      async_load16(X + (size_t)(rowBase + row) * NK + kt * BK + kk,
                   &xs[buf][j * 1024 + wave * 256]);
      async_load16(A + (size_t)(colBase + row) * NK + kt * BK + kk,
                   &as[buf][j * 1024 + wave * 256]);
    }
  };
  stage(0, 0);
  __syncthreads();
  int buf = 0;
#pragma unroll 1
  for (int kt = 0; kt < NK / BK; ++kt) {
    if (kt < NK / BK - 1) stage(buf ^ 1, kt + 1);
    const char* xb = (const char*)&xs[buf][0];
    const char* ab = (const char*)&as[buf][0];
#pragma unroll
    for (int s4 = 0; s4 < BK / 4; ++s4) {
      f32x4 xf[4], af[4];
#pragma unroll
      for (int r = 0; r < 4; ++r)
        xf[r] = *(const f32x4*)(xb + (xoff[r] ^ (uint32_t)(s4 << 4)));
#pragma unroll
      for (int c = 0; c < 4; ++c)
        af[c] = *(const f32x4*)(ab + (aoff[c] ^ (uint32_t)(s4 << 4)));
#pragma unroll
      for (int r = 0; r < 4; ++r)
#pragma unroll
        for (int c = 0; c < 4; ++c) {
          f32x4 s = xf[r] + af[c];
          float t0 = fmaxf(fmaxf(s.x, s.y), acc[r][c]);
          acc[r][c] = fmaxf(fmaxf(s.z, s.w), t0);
        }
    }
    __syncthreads();
    buf ^= 1;
  }
  const f32x4 bv = *(const f32x4*)&Bv[colBase + tx * 4];
  float bvv[4] = {bv.x, bv.y, bv.z, bv.w};
#pragma unroll
  for (int r = 0; r < 4; ++r) {
    f32x4 o;
    o.x = fmaxf(fmaxf(acc[r][0] - 1.0f, bvv[0]), 0.0f);
    o.y = fmaxf(fmaxf(acc[r][1] - 1.0f, bvv[1]), 0.0f);
    o.z = fmaxf(fmaxf(acc[r][2] - 1.0f, bvv[2]), 0.0f);
    o.w = fmaxf(fmaxf(acc[r][3] - 1.0f, bvv[3]), 0.0f);
    *(f32x4*)&Y[(size_t)(rowBase + ty * 4 + r) * NCOL + colBase + tx * 4] = o;
  }
}

extern "C" void kernel_launch(void* const* d_in, const int* in_sizes, int n_in,
                              void* d_out, int out_size, void* d_ws, size_t ws_size,
                              hipStream_t stream) {
  const float* X = (const float*)d_in[0];   // [2048][512]
  const float* A = (const float*)d_in[1];   // [512][512]
  const float* B = (const float*)d_in[2];   // [512]
  float* Y = (float*)d_out;                 // [2048][512]

  if (ws_size >= (size_t)NCOL * NK * sizeof(float)) {
    f32x4* Apb = (f32x4*)d_ws;
    luka_prep<<<dim3(NCOL * NK / 4 / 256), dim3(256), 0, stream>>>(A, Apb);
    dim3 grid(NCOL / CB, NROW / RPB);       // (8, 128) = 1024 blocks, 4/CU
    luka_main<<<grid, dim3(512), 0, stream>>>(Apb, X, B, Y);
  } else {
    dim3 grid(NCOL / TILE, NROW / TILE);    // fallback: R1 kernel
    luka_fb<<<grid, dim3(256), 0, stream>>>(X, A, B, Y);
  }
}

// Round 7
// 84.445 us; speedup vs baseline: 1.8760x; 1.0416x over previous
//
#include <hip/hip_runtime.h>
#include <cstdint>

// Lukasiewicz max-plus matmul: y[n,o] = max(b[o], max(0, max_i(x[n,i]+a[o,i]-1)))
// N=2048, K=512, OUT=512, fp32.
//
// R7: widen to 2 cols/lane. R6's ds:VALU ratio (1:4) made the per-CU LDS
// broadcast pipe co-critical with VALU; 2 cols/lane halves it to 1:8 and
// halves A L2-traffic (128MB). Block = 16 rows x 128 cols, 512 thr, 8-way
// intra-block k-split (duplicate-free loads), X slab 32KB in LDS consumed as
// broadcast ds_read_b128, A per-lane from transposed Apb. K-merge on-chip
// via 2 half-tile LDS passes (no atomics, no z-split). launch_bounds(512,4)
// -> VGPR cap 128 (R6's 64-cap starved A-prefetch depth).

#define NROW 2048
#define NK   512
#define NCOL 512
#define RPB  16                   // rows per block
#define CBL  128                  // cols per block (2 per lane)
#define KQ   16                   // k4-steps per wave (128 / 8 waves)
typedef float f32x4 __attribute__((ext_vector_type(4)));

__device__ __forceinline__ void async_load16(const float* g, float* l) {
  __builtin_amdgcn_global_load_lds(
      (const __attribute__((address_space(1))) void*)g,
      (__attribute__((address_space(3))) void*)l, 16, 0, 0);
}

// ---- prep: Apb[((col>>7)*128 + k4)*128 + (col&127)] = A[col][4k4..4k4+3] --
__global__ __launch_bounds__(256) void luka_prep(const float* __restrict__ A,
                                                 f32x4* __restrict__ Apb) {
  int idx = blockIdx.x * 256 + threadIdx.x;   // 512 cols * 128 k4
  int o  = idx >> 7;
  int k4 = idx & 127;
  f32x4 v = *(const f32x4*)(A + o * NK + k4 * 4);      // coalesced read
  Apb[(((o >> 7) * 128) + k4) * 128 + (o & 127)] = v;  // 1MB one-shot
}

// ---- main -----------------------------------------------------------------
__global__ __launch_bounds__(512, 4) void luka_main(
    const f32x4* __restrict__ Apb, const float* __restrict__ X,
    const float* __restrict__ Bv, float* __restrict__ Y) {
  __shared__ float lds[RPB * NK];             // 32KB: X slab, then reduction
  const int tid  = threadIdx.x;
  const int lane = tid & 63;
  const int w    = tid >> 6;                  // wave id = K-eighth
  const int colblk  = blockIdx.x;             // 0..3
  const int rowBase = blockIdx.y * RPB;

  // Stage X[rowBase..+16)[0..512) -> lds row-major [16][512]; 2048 f32x4 by
  // 512 threads in 4 rounds; per-wave LDS dest linear (base + lane*16) ✓.
  {
    const float* Xg = X + (size_t)rowBase * NK;
#pragma unroll
    for (int rnd = 0; rnd < 4; ++rnd) {
      int base = rnd * 512 + w * 64;          // f32x4 index, wave-uniform
      async_load16(Xg + (size_t)(base + lane) * 4, &lds[base * 4]);
    }
  }

  // Wave's A stream: cols {lane, lane+64} of colblk panel, k-eighth w.
  const f32x4* __restrict__ Aw =
      Apb + ((size_t)(colblk * 128 + w * KQ) * 128 + lane);

  float acc[RPB][2];
#pragma unroll
  for (int r = 0; r < RPB; ++r) { acc[r][0] = 0.0f; acc[r][1] = 0.0f; }

  __syncthreads();                            // staged X visible (vm drain)

#pragma unroll 4
  for (int j = 0; j < KQ; ++j) {
    const f32x4 a0 = Aw[j * 128];             // L1/L2 pipe: 1KB coalesced
    const f32x4 a1 = Aw[j * 128 + 64];        // +1KB (imm offset)
    const int kb = (w * KQ + j) * 4;          // float col within x row
#pragma unroll
    for (int r = 0; r < RPB; ++r) {
      // LDS pipe: wave-uniform broadcast ds_read_b128 (conflict-free),
      // one read amortized over 2 cols -> ds:VALU = 1:8.
      const f32x4 xv = *(const f32x4*)&lds[r * NK + kb];
      f32x4 s0 = a0 + xv;                     // v_pk_add_f32 x2
      f32x4 s1 = a1 + xv;
      acc[r][0] = fmaxf(fmaxf(s0.x, s0.y), acc[r][0]);  // v_max3
      acc[r][0] = fmaxf(fmaxf(s0.z, s0.w), acc[r][0]);
      acc[r][1] = fmaxf(fmaxf(s1.x, s1.y), acc[r][1]);
      acc[r][1] = fmaxf(fmaxf(s1.z, s1.w), acc[r][1]);
    }
  }

  // 8-way K-merge, two half-tiles of 8 rows, reusing the 32KB slab as
  // red[8 waves][8 rows][128 cols] (exactly 32KB). No atomics, plain stores.
  const float bv = Bv[colblk * CBL + (tid & 127)];  // col for reduce phase
  __syncthreads();                            // all waves done reading X slab
#pragma unroll 1
  for (int half = 0; half < 2; ++half) {
#pragma unroll
    for (int r = 0; r < 8; ++r) {             // write my partials
      lds[(w * 8 + r) * CBL + lane]      = acc[half * 8 + r][0];
      lds[(w * 8 + r) * CBL + 64 + lane] = acc[half * 8 + r][1];
    }
    __syncthreads();
#pragma unroll
    for (int e0 = 0; e0 < 2; ++e0) {          // 1024 elems / 512 thr
      int e   = e0 * 512 + tid;
      int row = e >> 7, col = e & 127;        // col == tid&127 (512%128==0)
      float m = lds[row * CBL + col];
#pragma unroll
      for (int ww = 1; ww < 8; ++ww)
        m = fmaxf(m, lds[(ww * 8 + row) * CBL + col]);
      float t = m - 1.0f;                     // defer of -1 is exact
      Y[(size_t)(rowBase + half * 8 + row) * NCOL + colblk * CBL + col] =
          fmaxf(fmaxf(t, bv), 0.0f);          // v_max3
    }
    __syncthreads();                          // red region reused next half
  }
}

// ---- fallback (R1 kernel, used only if d_ws < 1MB) ------------------------
#define TILE 64
#define BK   64
__global__ __launch_bounds__(256) void luka_fb(
    const float* __restrict__ X, const float* __restrict__ A,
    const float* __restrict__ Bv, float* __restrict__ Y) {
  __shared__ float xs[2][TILE * BK];
  __shared__ float as[2][TILE * BK];
  const int tid = threadIdx.x, wave = tid >> 6, tx = tid & 15, ty = tid >> 4;
  const int rowBase = blockIdx.y * TILE, colBase = blockIdx.x * TILE;
  uint32_t xoff[4], aoff[4];
#pragma unroll
  for (int r = 0; r < 4; ++r) {
    int row = ty * 4 + r;
    xoff[r] = (uint32_t)row * 256u + ((uint32_t)((row & 15) ^ (row >> 2)) << 4);
  }
#pragma unroll
  for (int c = 0; c < 4; ++c) {
    int row = tx * 4 + c;
    aoff[c] = (uint32_t)row * 256u + ((uint32_t)((row & 15) ^ (row >> 2)) << 4);
  }
  float acc[4][4];
#pragma unroll
  for (int r = 0; r < 4; ++r)
#pragma unroll
    for (int c = 0; c < 4; ++c) acc[r][c] = 0.0f;
  const int row0 = tid >> 4, sl = tid & 15;
  auto stage = [&](int buf, int kt) {
#pragma unroll
    for (int j = 0; j < 4; ++j) {
      int row = row0 + j * 16;
      int m = (row & 15) ^ (row >> 2);
      int kk = ((sl ^ m) << 2);
      async_load16(X + (size_t)(rowBase + row) * NK + kt * BK + kk,
                   &xs[buf][j * 1024 + wave * 256]);
      async_load16(A + (size_t)(colBase + row) * NK + kt * BK + kk,
                   &as[buf][j * 1024 + wave * 256]);
    }
  };
  stage(0, 0);
  __syncthreads();
  int buf = 0;
#pragma unroll 1
  for (int kt = 0; kt < NK / BK; ++kt) {
    if (kt < NK / BK - 1) stage(buf ^ 1, kt + 1);
    const char* xb = (const char*)&xs[buf][0];
    const char* ab = (const char*)&as[buf][0];
#pragma unroll
    for (int s4 = 0; s4 < BK / 4; ++s4) {
      f32x4 xf[4], af[4];
#pragma unroll
      for (int r = 0; r < 4; ++r)
        xf[r] = *(const f32x4*)(xb + (xoff[r] ^ (uint32_t)(s4 << 4)));
#pragma unroll
      for (int c = 0; c < 4; ++c)
        af[c] = *(const f32x4*)(ab + (aoff[c] ^ (uint32_t)(s4 << 4)));
#pragma unroll
      for (int r = 0; r < 4; ++r)
#pragma unroll
        for (int c = 0; c < 4; ++c) {
          f32x4 s = xf[r] + af[c];
          float t0 = fmaxf(fmaxf(s.x, s.y), acc[r][c]);
          acc[r][c] = fmaxf(fmaxf(s.z, s.w), t0);
        }
    }
    __syncthreads();
    buf ^= 1;
  }
  const f32x4 bv = *(const f32x4*)&Bv[colBase + tx * 4];
  float bvv[4] = {bv.x, bv.y, bv.z, bv.w};
#pragma unroll
  for (int r = 0; r < 4; ++r) {
    f32x4 o;
    o.x = fmaxf(fmaxf(acc[r][0] - 1.0f, bvv[0]), 0.0f);
    o.y = fmaxf(fmaxf(acc[r][1] - 1.0f, bvv[1]), 0.0f);
    o.z = fmaxf(fmaxf(acc[r][2] - 1.0f, bvv[2]), 0.0f);
    o.w = fmaxf(fmaxf(acc[r][3] - 1.0f, bvv[3]), 0.0f);
    *(f32x4*)&Y[(size_t)(rowBase + ty * 4 + r) * NCOL + colBase + tx * 4] = o;
  }
}

extern "C" void kernel_launch(void* const* d_in, const int* in_sizes, int n_in,
                              void* d_out, int out_size, void* d_ws, size_t ws_size,
                              hipStream_t stream) {
  const float* X = (const float*)d_in[0];   // [2048][512]
  const float* A = (const float*)d_in[1];   // [512][512]
  const float* B = (const float*)d_in[2];   // [512]
  float* Y = (float*)d_out;                 // [2048][512]

  if (ws_size >= (size_t)NCOL * NK * sizeof(float)) {
    f32x4* Apb = (f32x4*)d_ws;
    luka_prep<<<dim3(NCOL * NK / 4 / 256), dim3(256), 0, stream>>>(A, Apb);
    dim3 grid(NCOL / CBL, NROW / RPB);      // (4, 128) = 512 blocks
    luka_main<<<grid, dim3(512), 0, stream>>>(Apb, X, B, Y);
  } else {
    dim3 grid(NCOL / TILE, NROW / TILE);    // fallback: R1 kernel
    luka_fb<<<grid, dim3(256), 0, stream>>>(X, A, B, Y);
  }
}